// Round 4
// baseline (405.129 us; speedup 1.0000x reference)
//
#include <hip/hip_runtime.h>
#include <hip/hip_bf16.h>
#include <math.h>

#define NPERSEG 128
#define HOP     64
#define NFRAMES 33
#define NFREQ   65
#define BATCH   2048
#define LEN     2048
#define NSENS   8
#define FEAT    (NFREQ * NFRAMES)   // 2145
#define FEATP   2176                // FEAT padded to multiple of 32
#define H1      1024
#define H2      512
#define H3      256
#define NOUT    10

// STFT-as-GEMM geometry
#define XROW    2264                // elems/row; 1132 words % 32 = 12 -> b128 quarter-groups tile all banks
#define CWROW   136
#define NB      160
#define NTILES  10
#define MT_PER_WAVE 3

typedef __attribute__((ext_vector_type(8))) short short8;     // 8 bf16 = 4 VGPRs
typedef __attribute__((ext_vector_type(4))) float float4v;    // MFMA C/D
typedef unsigned short ushort;
typedef unsigned int uint;

__device__ __forceinline__ ushort f2b(float v) {
    __hip_bfloat16 h = __float2bfloat16(v);
    return *reinterpret_cast<ushort*>(&h);
}
__device__ __forceinline__ uint pack2(float a, float b) {
    return (uint)f2b(a) | ((uint)f2b(b) << 16);
}
__device__ __forceinline__ float b2f(ushort u) {
    union { uint i; float f; } c; c.i = ((uint)u) << 16; return c.f;
}
__device__ __forceinline__ void gl_lds16(const void* g, void* l) {
    __builtin_amdgcn_global_load_lds(
        (const __attribute__((address_space(1))) unsigned int*)g,
        (__attribute__((address_space(3))) unsigned int*)l, 16, 0, 0);
}

// ---------------------------------------------------------------------------
// Kernel 0: softmax over the 8 sensor weights.
// ---------------------------------------------------------------------------
__global__ void sf_softmax8(const float* __restrict__ w, float* __restrict__ out) {
    if (threadIdx.x == 0) {
        float m = w[0];
        for (int s = 1; s < NSENS; ++s) m = fmaxf(m, w[s]);
        float e[NSENS];
        float sum = 0.f;
        for (int s = 0; s < NSENS; ++s) { e[s] = expf(w[s] - m); sum += e[s]; }
        float inv = 1.0f / sum;
        for (int s = 0; s < NSENS; ++s) out[s] = e[s] * inv;
    }
}

// ---------------------------------------------------------------------------
// Kernel 0b: windowed DFT basis in bf16 (window + 1/64 norm folded in).
// ---------------------------------------------------------------------------
__global__ void sf_basis(ushort* __restrict__ cwg) {
    int e = blockIdx.x * 256 + threadIdx.x;
    if (e >= NB * CWROW) return;
    int n = e / CWROW, k = e - n * CWROW;
    const float TWO_PI = 6.28318530717958647692f;
    float v = 0.f;
    if (k < NPERSEG) {
        float win = 0.5f - 0.5f * cosf(TWO_PI * (float)k / (float)NPERSEG);
        if (n < NFREQ) {
            int r = (n * k) & (NPERSEG - 1);
            v = win * cosf(TWO_PI * (float)r / (float)NPERSEG) * (1.0f / 64.0f);
        } else if (n >= 80 && n < 80 + NFREQ) {
            int r = ((n - 80) * k) & (NPERSEG - 1);
            v = win * sinf(TWO_PI * (float)r / (float)NPERSEG) * (1.0f / 64.0f);
        }
    }
    cwg[e] = f2b(v);
}

// ---------------------------------------------------------------------------
// Kernel 0c: fp32 -> bf16 weight convert with K padding (zeros in pad).
// ---------------------------------------------------------------------------
__global__ void sf_cvt_w(const float* __restrict__ src, ushort* __restrict__ dst,
                         int N, int K, int Kp) {
    int e = blockIdx.x * 256 + threadIdx.x;
    if (e >= N * Kp) return;
    int n = e / Kp, k = e - n * Kp;
    dst[e] = f2b(k < K ? src[(long)n * K + k] : 0.f);
}

// ---------------------------------------------------------------------------
// Kernel 1: STFT magnitude + sensor fusion via MFMA.
// Round-4 changes: no fuse[]/atomics (shfl_xor(16) sensor combine + direct
// bf16 scatter store), packed b32 LDS staging, basis via global_load_lds,
// XROW=2264 (conflict-free A frags), LDS 77.9 KB -> 2 blocks/CU.
// NOTE: h0 pad columns [2145,2176) are left unwritten (poison); safe because
// W1b pad rows are exact zeros, so pad A values never contribute.
// ---------------------------------------------------------------------------
__global__ __launch_bounds__(512, 4)
void sf_stft_fuse(const float* __restrict__ x,
                  const float* __restrict__ wsoft,
                  const ushort* __restrict__ cwg,
                  ushort* __restrict__ h0) {
    __shared__ __align__(16) ushort xbp[NSENS * XROW];   // 36.2 KB
    __shared__ __align__(16) ushort cw[NB * CWROW];      // 42.5 KB
    __shared__ float wsens[NSENS];

    const int b    = blockIdx.x;
    const int tid  = threadIdx.x;
    const int lane = tid & 63;
    const int wv   = tid >> 6;

    // ---- basis: async global->LDS, 16B chunks (2720 total), wave-uniform LDS base
    for (int c = wv; c < 43; c += 8) {
        int idx = c * 64 + lane;
        if (idx < (NB * CWROW) / 8)
            gl_lds16(cwg + idx * 8, &cw[c * 64 * 8]);
    }

    // ---- x staging: read float4 pairs, pack bf16x2, ds_write_b32 (conflict-free)
    const float4* xb4 = (const float4*)(x + (size_t)b * (LEN * NSENS));
    uint* xw = (uint*)xbp;
    for (int e = tid; e < 2048; e += 512) {
        int i = e >> 1;            // sample-pair index: l = 2i, 2i+1
        int h = e & 1;             // sensor half: s = 4h..4h+3
        float4 v0 = xb4[i * 4 + h];
        float4 v1 = xb4[i * 4 + 2 + h];
        int base = (h * 4) * (XROW / 2) + 32 + i;
        xw[base                 ] = pack2(v0.x, v1.x);
        xw[base +     (XROW / 2)] = pack2(v0.y, v1.y);
        xw[base + 2 * (XROW / 2)] = pack2(v0.z, v1.z);
        xw[base + 3 * (XROW / 2)] = pack2(v0.w, v1.w);
    }
    for (int e = tid; e < NSENS * 32; e += 512)          // left pad (64 elems)
        xw[(e >> 5) * (XROW / 2) + (e & 31)] = 0;
    for (int e = tid; e < NSENS * 76; e += 512) {        // right pad (152 elems)
        int s = e / 76;
        xw[s * (XROW / 2) + 1056 + (e - s * 76)] = 0;
    }
    if (tid < NSENS) wsens[tid] = wsoft[tid];
    __syncthreads();

    // ---- MFMA phase
    const int col = lane & 15;
    const int q   = lane >> 4;

    float wqa[4];
    *(float4*)wqa = *(const float4*)&wsens[(q & 1) * 4];

    const ushort* abase[MT_PER_WAVE];
    #pragma unroll
    for (int mb = 0; mb < MT_PER_WAVE; ++mb) {
        int mi = wv * MT_PER_WAVE + mb;          // 0..23
        int m  = mi * 16 + col;
        int ta = m >> 3; if (ta > NFRAMES) ta = NFRAMES;   // clamp into zero pad
        int sa = m & 7;
        abase[mb] = &xbp[sa * XROW + ta * HOP + q * 8];
    }

    float4v acc[MT_PER_WAVE][NTILES];
    #pragma unroll
    for (int mb = 0; mb < MT_PER_WAVE; ++mb)
        #pragma unroll
        for (int ni = 0; ni < NTILES; ++ni)
            acc[mb][ni] = (float4v){0.f, 0.f, 0.f, 0.f};

    #pragma unroll
    for (int ks = 0; ks < 4; ++ks) {
        short8 af[MT_PER_WAVE];
        #pragma unroll
        for (int mb = 0; mb < MT_PER_WAVE; ++mb)
            af[mb] = *(const short8*)(abase[mb] + ks * 32);
        #pragma unroll
        for (int ni = 0; ni < NTILES; ++ni) {
            short8 bf = *(const short8*)&cw[(ni * 16 + col) * CWROW + ks * 32 + q * 8];
            #pragma unroll
            for (int mb = 0; mb < MT_PER_WAVE; ++mb)
                acc[mb][ni] = __builtin_amdgcn_mfma_f32_16x16x32_bf16(af[mb], bf, acc[mb][ni], 0, 0, 0);
        }
    }

    // ---- epilogue: mag, sensor fuse via shfl_xor(16), direct scatter store
    ushort* h0b = h0 + (size_t)b * FEATP;
    #pragma unroll
    for (int mb = 0; mb < MT_PER_WAVE; ++mb) {
        int mi = wv * MT_PER_WAVE + mb;
        int t  = mi * 2 + (q >> 1);
        #pragma unroll
        for (int ni = 0; ni < 5; ++ni) {         // re tile ni, im tile ni+5
            float ps = 0.f;
            #pragma unroll
            for (int r = 0; r < 4; ++r) {
                float re = acc[mb][ni][r];
                float im = acc[mb][ni + 5][r];
                ps += wqa[r] * sqrtf(re * re + im * im);
            }
            float tot = ps + __shfl_xor(ps, 16, 64);
            int f = ni * 16 + col;
            if (((q & 1) == 0) && t < NFRAMES && f < NFREQ)
                h0b[f * NFRAMES + t] = f2b(tot);
        }
    }
}

// ---------------------------------------------------------------------------
// Kernel 2: bf16 MFMA NT-GEMM, m97 structure (verified round 3, unchanged).
// ---------------------------------------------------------------------------
template <int RELU>
__global__ __launch_bounds__(256)
void sf_gemm_mfma(const ushort* __restrict__ A, const ushort* __restrict__ W,
                  const float* __restrict__ bias, ushort* __restrict__ C,
                  int M, int N, int K) {
    __shared__ __align__(16) ushort As[128 * 32];
    __shared__ __align__(16) ushort Bs[128 * 32];

    const int tid  = threadIdx.x;
    const int lane = tid & 63;
    const int wv   = tid >> 6;
    const int wrow = wv >> 1;
    const int wcol = wv & 1;
    const int col  = lane & 15;
    const int q    = lane >> 4;

    const int m0 = blockIdx.y * 128;
    const int n0 = blockIdx.x * 128;

    const int srow = lane >> 2;
    const int skch = (lane & 3) ^ ((lane >> 3) & 3);

    float4v acc[4][4];
    #pragma unroll
    for (int mi = 0; mi < 4; ++mi)
        #pragma unroll
        for (int ni = 0; ni < 4; ++ni)
            acc[mi][ni] = (float4v){0.f, 0.f, 0.f, 0.f};

    const int fsw = ((col >> 1) & 3);
    int aoff[4], boff[4];
    #pragma unroll
    for (int i = 0; i < 4; ++i) {
        aoff[i] = (wrow * 64 + i * 16 + col) * 32 + ((q ^ fsw) * 8);
        boff[i] = (wcol * 64 + i * 16 + col) * 32 + ((q ^ fsw) * 8);
    }

    for (int k0 = 0; k0 < K; k0 += 32) {
        #pragma unroll
        for (int i = 0; i < 2; ++i) {
            int c = wv * 2 + i;
            int r = c * 16 + srow;
            gl_lds16(A + (size_t)(m0 + r) * K + k0 + skch * 8, &As[c * 16 * 32]);
            gl_lds16(W + (size_t)(n0 + r) * K + k0 + skch * 8, &Bs[c * 16 * 32]);
        }
        __syncthreads();

        short8 af[4], bf[4];
        #pragma unroll
        for (int i = 0; i < 4; ++i) {
            af[i] = *(const short8*)&As[aoff[i]];
            bf[i] = *(const short8*)&Bs[boff[i]];
        }
        #pragma unroll
        for (int mi = 0; mi < 4; ++mi)
            #pragma unroll
            for (int ni = 0; ni < 4; ++ni)
                acc[mi][ni] = __builtin_amdgcn_mfma_f32_16x16x32_bf16(af[mi], bf[ni], acc[mi][ni], 0, 0, 0);
        __syncthreads();
    }

    #pragma unroll
    for (int ni = 0; ni < 4; ++ni) {
        int n = n0 + wcol * 64 + ni * 16 + col;
        float bn = bias[n];
        #pragma unroll
        for (int mi = 0; mi < 4; ++mi) {
            int mbase = m0 + wrow * 64 + mi * 16 + q * 4;
            #pragma unroll
            for (int r = 0; r < 4; ++r) {
                float v = acc[mi][ni][r] + bn;
                if (RELU) v = fmaxf(v, 0.f);
                C[(size_t)(mbase + r) * N + n] = f2b(v);
            }
        }
    }
}

// ---------------------------------------------------------------------------
// Kernel 3: final tiny layer, fp32 out.
// ---------------------------------------------------------------------------
__global__ __launch_bounds__(256)
void sf_final(const ushort* __restrict__ h3, const float* __restrict__ W4,
              const float* __restrict__ b4, float* __restrict__ out) {
    int o = blockIdx.x * 256 + threadIdx.x;
    if (o >= BATCH * NOUT) return;
    int m = o / NOUT, n = o - m * NOUT;
    const ushort* a = h3 + (size_t)m * H3;
    const float* w = W4 + (size_t)n * H3;
    float s = 0.f;
    #pragma unroll 8
    for (int k = 0; k < H3; ++k) s = fmaf(b2f(a[k]), w[k], s);
    out[o] = s + b4[n];
}

// ---------------------------------------------------------------------------
extern "C" void kernel_launch(void* const* d_in, const int* in_sizes, int n_in,
                              void* d_out, int out_size, void* d_ws, size_t ws_size,
                              hipStream_t stream) {
    const float* x  = (const float*)d_in[0];
    const float* sw = (const float*)d_in[1];
    const float* W1 = (const float*)d_in[2];
    const float* b1 = (const float*)d_in[3];
    const float* W2 = (const float*)d_in[4];
    const float* b2 = (const float*)d_in[5];
    const float* W3 = (const float*)d_in[6];
    const float* b3 = (const float*)d_in[7];
    const float* W4 = (const float*)d_in[8];
    const float* b4 = (const float*)d_in[9];
    float* out = (float*)d_out;

    char* cur = (char*)d_ws;
    float* wsoft = (float*)cur;                 cur += 64;
    ushort* cwg  = (ushort*)cur;                cur += NB * CWROW * 2;
    ushort* h0   = (ushort*)cur;                cur += (size_t)BATCH * FEATP * 2;
    ushort* W1b  = (ushort*)cur;                cur += (size_t)H1 * FEATP * 2;
    ushort* W2b  = (ushort*)cur;                cur += (size_t)H2 * H1 * 2;
    ushort* W3b  = (ushort*)cur;                cur += (size_t)H3 * H2 * 2;
    ushort* h1   = (ushort*)cur;                cur += (size_t)BATCH * H1 * 2;
    ushort* h2   = (ushort*)cur;                cur += (size_t)BATCH * H2 * 2;
    ushort* h3   = (ushort*)cur;                cur += (size_t)BATCH * H3 * 2;

    sf_softmax8<<<1, 64, 0, stream>>>(sw, wsoft);
    sf_basis<<<(NB * CWROW + 255) / 256, 256, 0, stream>>>(cwg);
    sf_cvt_w<<<(H1 * FEATP + 255) / 256, 256, 0, stream>>>(W1, W1b, H1, FEAT, FEATP);
    sf_cvt_w<<<(H2 * H1 + 255) / 256, 256, 0, stream>>>(W2, W2b, H2, H1, H1);
    sf_cvt_w<<<(H3 * H2 + 255) / 256, 256, 0, stream>>>(W3, W3b, H3, H2, H2);

    sf_stft_fuse<<<BATCH, 512, 0, stream>>>(x, wsoft, cwg, h0);

    sf_gemm_mfma<1><<<dim3(H1 / 128, BATCH / 128), 256, 0, stream>>>(h0, W1b, b1, h1, BATCH, H1, FEATP);
    sf_gemm_mfma<1><<<dim3(H2 / 128, BATCH / 128), 256, 0, stream>>>(h1, W2b, b2, h2, BATCH, H2, H1);
    sf_gemm_mfma<1><<<dim3(H3 / 128, BATCH / 128), 256, 0, stream>>>(h2, W3b, b3, h3, BATCH, H3, H2);
    sf_final<<<(BATCH * NOUT + 255) / 256, 256, 0, stream>>>(h3, W4, b4, out);
}

// Round 5
// 328.823 us; speedup vs baseline: 1.2321x; 1.2321x over previous
//
#include <hip/hip_runtime.h>
#include <hip/hip_bf16.h>
#include <math.h>

#define NPERSEG 128
#define HOP     64
#define NFRAMES 33
#define NFREQ   65
#define BATCH   2048
#define LEN     2048
#define NSENS   8
#define FEAT    (NFREQ * NFRAMES)   // 2145
#define FEATP   2176                // FEAT padded to multiple of 32
#define H1      1024
#define H2      512
#define H3      256
#define NOUT    10

// STFT-as-GEMM geometry
#define XROW    2264                // elems/row; 1132 words % 32 = 12
#define CWROW   136
#define NB      160
#define MT_PER_WAVE 3

typedef __attribute__((ext_vector_type(8))) short short8;     // 8 bf16 = 4 VGPRs
typedef __attribute__((ext_vector_type(4))) float float4v;    // MFMA C/D
typedef unsigned short ushort;
typedef unsigned int uint;

__device__ __forceinline__ ushort f2b(float v) {
    __hip_bfloat16 h = __float2bfloat16(v);
    return *reinterpret_cast<ushort*>(&h);
}
__device__ __forceinline__ uint pack2(float a, float b) {
    return (uint)f2b(a) | ((uint)f2b(b) << 16);
}
__device__ __forceinline__ float b2f(ushort u) {
    union { uint i; float f; } c; c.i = ((uint)u) << 16; return c.f;
}
__device__ __forceinline__ float b2fu(uint lo16) {
    union { uint i; float f; } c; c.i = lo16 << 16; return c.f;
}
__device__ __forceinline__ void gl_lds16(const void* g, void* l) {
    __builtin_amdgcn_global_load_lds(
        (const __attribute__((address_space(1))) unsigned int*)g,
        (__attribute__((address_space(3))) unsigned int*)l, 16, 0, 0);
}

// ---------------------------------------------------------------------------
// Kernel 0: softmax over the 8 sensor weights.
// ---------------------------------------------------------------------------
__global__ void sf_softmax8(const float* __restrict__ w, float* __restrict__ out) {
    if (threadIdx.x == 0) {
        float m = w[0];
        for (int s = 1; s < NSENS; ++s) m = fmaxf(m, w[s]);
        float e[NSENS];
        float sum = 0.f;
        for (int s = 0; s < NSENS; ++s) { e[s] = expf(w[s] - m); sum += e[s]; }
        float inv = 1.0f / sum;
        for (int s = 0; s < NSENS; ++s) out[s] = e[s] * inv;
    }
}

// ---------------------------------------------------------------------------
// Kernel 0b: windowed DFT basis in bf16 (window + 1/64 norm folded in).
// ---------------------------------------------------------------------------
__global__ void sf_basis(ushort* __restrict__ cwg) {
    int e = blockIdx.x * 256 + threadIdx.x;
    if (e >= NB * CWROW) return;
    int n = e / CWROW, k = e - n * CWROW;
    const float TWO_PI = 6.28318530717958647692f;
    float v = 0.f;
    if (k < NPERSEG) {
        float win = 0.5f - 0.5f * cosf(TWO_PI * (float)k / (float)NPERSEG);
        if (n < NFREQ) {
            int r = (n * k) & (NPERSEG - 1);
            v = win * cosf(TWO_PI * (float)r / (float)NPERSEG) * (1.0f / 64.0f);
        } else if (n >= 80 && n < 80 + NFREQ) {
            int r = ((n - 80) * k) & (NPERSEG - 1);
            v = win * sinf(TWO_PI * (float)r / (float)NPERSEG) * (1.0f / 64.0f);
        }
    }
    cwg[e] = f2b(v);
}

// ---------------------------------------------------------------------------
// Kernel 0c: fp32 -> bf16 weight convert with K padding (zeros in pad).
// ---------------------------------------------------------------------------
__global__ void sf_cvt_w(const float* __restrict__ src, ushort* __restrict__ dst,
                         int N, int K, int Kp) {
    int e = blockIdx.x * 256 + threadIdx.x;
    if (e >= N * Kp) return;
    int n = e / Kp, k = e - n * Kp;
    dst[e] = f2b(k < K ? src[(long)n * K + k] : 0.f);
}

// ---------------------------------------------------------------------------
// Kernel 1: STFT magnitude + sensor fusion via MFMA.
// Round-5: (1) B-frags read directly from global cwg (L1/L2-resident; kills
// the 8-way LDS conflicts and frees 42.5 KB LDS -> 3 blocks/CU);
// (2) re/im N-tile pairs with full-K accumulation per pair (acc 120->24 regs);
// (3) h0 written via LDS hstage then coalesced uint2 stores (kills the
// partial-line RMW thrash that round 4 introduced: WRITE 225 MB -> ~10 MB).
// ---------------------------------------------------------------------------
__global__ __launch_bounds__(512, 4)
void sf_stft_fuse(const float* __restrict__ x,
                  const float* __restrict__ wsoft,
                  const ushort* __restrict__ cwg,
                  ushort* __restrict__ h0) {
    __shared__ __align__(16) ushort xbp[NSENS * XROW];   // 36.2 KB
    __shared__ __align__(16) ushort hstage[FEATP];       // 4.4 KB
    __shared__ float wsens[NSENS];

    const int b    = blockIdx.x;
    const int tid  = threadIdx.x;
    const int lane = tid & 63;
    const int wv   = tid >> 6;

    // ---- x staging: read float4 pairs, pack bf16x2, ds_write_b32
    const float4* xb4 = (const float4*)(x + (size_t)b * (LEN * NSENS));
    uint* xw = (uint*)xbp;
    for (int e = tid; e < 2048; e += 512) {
        int i = e >> 1;            // sample-pair index: l = 2i, 2i+1
        int h = e & 1;             // sensor half: s = 4h..4h+3
        float4 v0 = xb4[i * 4 + h];
        float4 v1 = xb4[i * 4 + 2 + h];
        int base = (h * 4) * (XROW / 2) + 32 + i;
        xw[base                 ] = pack2(v0.x, v1.x);
        xw[base +     (XROW / 2)] = pack2(v0.y, v1.y);
        xw[base + 2 * (XROW / 2)] = pack2(v0.z, v1.z);
        xw[base + 3 * (XROW / 2)] = pack2(v0.w, v1.w);
    }
    for (int e = tid; e < NSENS * 32; e += 512)          // left pad (64 elems)
        xw[(e >> 5) * (XROW / 2) + (e & 31)] = 0;
    for (int e = tid; e < NSENS * 76; e += 512) {        // right pad (152 elems)
        int s = e / 76;
        xw[s * (XROW / 2) + 1056 + (e - s * 76)] = 0;
    }
    if (tid < FEATP - FEAT) hstage[FEAT + tid] = 0;      // zero K-pad cols
    if (tid < NSENS) wsens[tid] = wsoft[tid];
    __syncthreads();

    // ---- MFMA phase (re/im pair-structured)
    const int col = lane & 15;
    const int q   = lane >> 4;

    float wqa[4];
    *(float4*)wqa = *(const float4*)&wsens[(q & 1) * 4];

    const ushort* abase[MT_PER_WAVE];
    #pragma unroll
    for (int mb = 0; mb < MT_PER_WAVE; ++mb) {
        int mi = wv * MT_PER_WAVE + mb;          // 0..23
        int m  = mi * 16 + col;
        int ta = m >> 3; if (ta > NFRAMES) ta = NFRAMES;   // clamp into zero pad
        int sa = m & 7;
        abase[mb] = &xbp[sa * XROW + ta * HOP + q * 8];
    }

    #pragma unroll 1
    for (int np = 0; np < 5; ++np) {             // re tile np, im tile np+5
        float4v accR[MT_PER_WAVE], accI[MT_PER_WAVE];
        #pragma unroll
        for (int mb = 0; mb < MT_PER_WAVE; ++mb) {
            accR[mb] = (float4v){0.f, 0.f, 0.f, 0.f};
            accI[mb] = (float4v){0.f, 0.f, 0.f, 0.f};
        }
        #pragma unroll
        for (int ks = 0; ks < 4; ++ks) {
            short8 bR = *(const short8*)&cwg[(np * 16 + col) * CWROW + ks * 32 + q * 8];
            short8 bI = *(const short8*)&cwg[((np + 5) * 16 + col) * CWROW + ks * 32 + q * 8];
            #pragma unroll
            for (int mb = 0; mb < MT_PER_WAVE; ++mb) {
                short8 af = *(const short8*)(abase[mb] + ks * 32);
                accR[mb] = __builtin_amdgcn_mfma_f32_16x16x32_bf16(af, bR, accR[mb], 0, 0, 0);
                accI[mb] = __builtin_amdgcn_mfma_f32_16x16x32_bf16(af, bI, accI[mb], 0, 0, 0);
            }
        }
        // epilogue for this pair: mag, sensor fuse via shfl_xor(16), LDS scatter
        int f = np * 16 + col;
        #pragma unroll
        for (int mb = 0; mb < MT_PER_WAVE; ++mb) {
            float ps = 0.f;
            #pragma unroll
            for (int r = 0; r < 4; ++r) {
                float re = accR[mb][r];
                float im = accI[mb][r];
                ps += wqa[r] * sqrtf(re * re + im * im);
            }
            float tot = ps + __shfl_xor(ps, 16, 64);
            int mi = wv * MT_PER_WAVE + mb;
            int t  = mi * 2 + (q >> 1);
            if (((q & 1) == 0) && t < NFRAMES && f < NFREQ)
                hstage[f * NFRAMES + t] = f2b(tot);
        }
    }
    __syncthreads();

    // ---- coalesced h0 write (8 B/lane)
    const uint2* hsw = (const uint2*)hstage;
    uint2* ho = (uint2*)(h0 + (size_t)b * FEATP);
    for (int e = tid; e < FEATP / 4; e += 512)
        ho[e] = hsw[e];
}

// ---------------------------------------------------------------------------
// Kernel 2: bf16 MFMA NT-GEMM, m97 structure; BM=128, BN/WM/WN templated.
// 256 thr (4 waves). Staging via global_load_lds width 16 with XOR-chunk
// swizzle. M mult of 128, N mult of BN, K mult of 32. Output bf16.
// ---------------------------------------------------------------------------
template <int BN, int WM, int WN, int RELU>
__global__ __launch_bounds__(256)
void sf_gemm_mfma(const ushort* __restrict__ A, const ushort* __restrict__ W,
                  const float* __restrict__ bias, ushort* __restrict__ C,
                  int M, int N, int K) {
    const int MT = WM / 16, NT = WN / 16;
    const int NWN = BN / WN;               // waves along n
    __shared__ __align__(16) ushort As[128 * 32];
    __shared__ __align__(16) ushort Bs[BN * 32];

    const int tid  = threadIdx.x;
    const int lane = tid & 63;
    const int wv   = tid >> 6;
    const int wvm  = wv / NWN;
    const int wvn  = wv % NWN;
    const int col  = lane & 15;
    const int q    = lane >> 4;

    const int m0 = blockIdx.y * 128;
    const int n0 = blockIdx.x * BN;

    const int srow = lane >> 2;
    const int skch = (lane & 3) ^ ((lane >> 3) & 3);
    const int TC   = (128 + BN) / 16;      // total 16-row staging chunks

    float4v acc[MT][NT];
    #pragma unroll
    for (int mi = 0; mi < MT; ++mi)
        #pragma unroll
        for (int ni = 0; ni < NT; ++ni)
            acc[mi][ni] = (float4v){0.f, 0.f, 0.f, 0.f};

    const int fsw = ((col >> 1) & 3);
    int aoff[MT], boff[NT];
    #pragma unroll
    for (int i = 0; i < MT; ++i)
        aoff[i] = (wvm * WM + i * 16 + col) * 32 + ((q ^ fsw) * 8);
    #pragma unroll
    for (int j = 0; j < NT; ++j)
        boff[j] = (wvn * WN + j * 16 + col) * 32 + ((q ^ fsw) * 8);

    for (int k0 = 0; k0 < K; k0 += 32) {
        #pragma unroll
        for (int c = wv; c < TC; c += 4) {
            if (c < 8)
                gl_lds16(A + (size_t)(m0 + c * 16 + srow) * K + k0 + skch * 8,
                         &As[c * 16 * 32]);
            else
                gl_lds16(W + (size_t)(n0 + (c - 8) * 16 + srow) * K + k0 + skch * 8,
                         &Bs[(c - 8) * 16 * 32]);
        }
        __syncthreads();

        short8 af[MT], bf[NT];
        #pragma unroll
        for (int i = 0; i < MT; ++i) af[i] = *(const short8*)&As[aoff[i]];
        #pragma unroll
        for (int j = 0; j < NT; ++j) bf[j] = *(const short8*)&Bs[boff[j]];
        #pragma unroll
        for (int mi = 0; mi < MT; ++mi)
            #pragma unroll
            for (int ni = 0; ni < NT; ++ni)
                acc[mi][ni] = __builtin_amdgcn_mfma_f32_16x16x32_bf16(af[mi], bf[ni], acc[mi][ni], 0, 0, 0);
        __syncthreads();
    }

    #pragma unroll
    for (int ni = 0; ni < NT; ++ni) {
        int n = n0 + wvn * WN + ni * 16 + col;
        float bn = bias[n];
        #pragma unroll
        for (int mi = 0; mi < MT; ++mi) {
            int mbase = m0 + wvm * WM + mi * 16 + q * 4;
            #pragma unroll
            for (int r = 0; r < 4; ++r) {
                float v = acc[mi][ni][r] + bn;
                if (RELU) v = fmaxf(v, 0.f);
                C[(size_t)(mbase + r) * N + n] = f2b(v);
            }
        }
    }
}

// ---------------------------------------------------------------------------
// Kernel 3: final tiny layer, fp32 out, vectorized loads.
// ---------------------------------------------------------------------------
__global__ __launch_bounds__(256)
void sf_final(const ushort* __restrict__ h3, const float* __restrict__ W4,
              const float* __restrict__ b4, float* __restrict__ out) {
    int o = blockIdx.x * 256 + threadIdx.x;
    if (o >= BATCH * NOUT) return;
    int m = o / NOUT, n = o - m * NOUT;
    const uint2*  av = (const uint2*)(h3 + (size_t)m * H3);   // 4 bf16 per uint2
    const float4* wv4 = (const float4*)(W4 + (size_t)n * H3);
    float s = 0.f;
    #pragma unroll 8
    for (int j = 0; j < H3 / 4; ++j) {
        uint2 a = av[j];
        float4 w = wv4[j];
        s = fmaf(b2fu(a.x & 0xffffu), w.x, s);
        s = fmaf(b2fu(a.x >> 16),     w.y, s);
        s = fmaf(b2fu(a.y & 0xffffu), w.z, s);
        s = fmaf(b2fu(a.y >> 16),     w.w, s);
    }
    out[o] = s + b4[n];
}

// ---------------------------------------------------------------------------
extern "C" void kernel_launch(void* const* d_in, const int* in_sizes, int n_in,
                              void* d_out, int out_size, void* d_ws, size_t ws_size,
                              hipStream_t stream) {
    const float* x  = (const float*)d_in[0];
    const float* sw = (const float*)d_in[1];
    const float* W1 = (const float*)d_in[2];
    const float* b1 = (const float*)d_in[3];
    const float* W2 = (const float*)d_in[4];
    const float* b2 = (const float*)d_in[5];
    const float* W3 = (const float*)d_in[6];
    const float* b3 = (const float*)d_in[7];
    const float* W4 = (const float*)d_in[8];
    const float* b4 = (const float*)d_in[9];
    float* out = (float*)d_out;

    char* cur = (char*)d_ws;
    float* wsoft = (float*)cur;                 cur += 64;
    ushort* cwg  = (ushort*)cur;                cur += NB * CWROW * 2;
    ushort* h0   = (ushort*)cur;                cur += (size_t)BATCH * FEATP * 2;
    ushort* W1b  = (ushort*)cur;                cur += (size_t)H1 * FEATP * 2;
    ushort* W2b  = (ushort*)cur;                cur += (size_t)H2 * H1 * 2;
    ushort* W3b  = (ushort*)cur;                cur += (size_t)H3 * H2 * 2;
    ushort* h1   = (ushort*)cur;                cur += (size_t)BATCH * H1 * 2;
    ushort* h2   = (ushort*)cur;                cur += (size_t)BATCH * H2 * 2;
    ushort* h3   = (ushort*)cur;                cur += (size_t)BATCH * H3 * 2;

    sf_softmax8<<<1, 64, 0, stream>>>(sw, wsoft);
    sf_basis<<<(NB * CWROW + 255) / 256, 256, 0, stream>>>(cwg);
    sf_cvt_w<<<(H1 * FEATP + 255) / 256, 256, 0, stream>>>(W1, W1b, H1, FEAT, FEATP);
    sf_cvt_w<<<(H2 * H1 + 255) / 256, 256, 0, stream>>>(W2, W2b, H2, H1, H1);
    sf_cvt_w<<<(H3 * H2 + 255) / 256, 256, 0, stream>>>(W3, W3b, H3, H2, H2);

    sf_stft_fuse<<<BATCH, 512, 0, stream>>>(x, wsoft, cwg, h0);

    sf_gemm_mfma<64, 32, 64, 1><<<dim3(H1 / 64, BATCH / 128), 256, 0, stream>>>(h0, W1b, b1, h1, BATCH, H1, FEATP);
    sf_gemm_mfma<64, 32, 64, 1><<<dim3(H2 / 64, BATCH / 128), 256, 0, stream>>>(h1, W2b, b2, h2, BATCH, H2, H1);
    sf_gemm_mfma<64, 32, 64, 1><<<dim3(H3 / 64, BATCH / 128), 256, 0, stream>>>(h2, W3b, b3, h3, BATCH, H3, H2);
    sf_final<<<(BATCH * NOUT + 255) / 256, 256, 0, stream>>>(h3, W4, b4, out);
}

// Round 6
// 297.382 us; speedup vs baseline: 1.3623x; 1.1057x over previous
//
#include <hip/hip_runtime.h>
#include <hip/hip_bf16.h>
#include <math.h>

#define NPERSEG 128
#define HOP     64
#define NFRAMES 33
#define NFREQ   65
#define BATCH   2048
#define LEN     2048
#define NSENS   8
#define FEAT    (NFREQ * NFRAMES)   // 2145
#define FEATP   2176                // FEAT padded to multiple of 64
#define H1      1024
#define H2      512
#define H3      256
#define NOUT    10

// STFT-as-GEMM geometry
#define XROW    2264                // elems/row; 1132 words % 32 = 12
#define MT_PER_WAVE 3
#define NCWS    (10 * 4 * 64 * 8)   // 20480 basis elems, fragment-ordered

typedef __attribute__((ext_vector_type(8))) short short8;     // 8 bf16 = 4 VGPRs
typedef __attribute__((ext_vector_type(4))) float float4v;    // MFMA C/D
typedef unsigned short ushort;
typedef unsigned int uint;

__device__ __forceinline__ ushort f2b(float v) {
    __hip_bfloat16 h = __float2bfloat16(v);
    return *reinterpret_cast<ushort*>(&h);
}
__device__ __forceinline__ uint pack2(float a, float b) {
    return (uint)f2b(a) | ((uint)f2b(b) << 16);
}
__device__ __forceinline__ float b2fu(uint lo16) {
    union { uint i; float f; } c; c.i = lo16 << 16; return c.f;
}
__device__ __forceinline__ void gl_lds16(const void* g, void* l) {
    __builtin_amdgcn_global_load_lds(
        (const __attribute__((address_space(1))) unsigned int*)g,
        (__attribute__((address_space(3))) unsigned int*)l, 16, 0, 0);
}

// ---------------------------------------------------------------------------
// Kernel 0: fused prep — fragment-ordered DFT basis + 3 weight converts.
// cws layout: [(tile*4+ks)*64 + lane]*8 + j  holds  basis[n=tile*16+(lane&15)]
//             [k=ks*32+(lane>>4)*8+j]  (window + 1/64 folded; tiles 0-4 = cos,
//             5-9 = sin at rows 80+; rows 65-79 / 145-159 are zero).
// ---------------------------------------------------------------------------
__global__ __launch_bounds__(256)
void sf_prep(const float* __restrict__ W1, const float* __restrict__ W2,
             const float* __restrict__ W3,
             ushort* __restrict__ cws, ushort* __restrict__ W1b,
             ushort* __restrict__ W2b, ushort* __restrict__ W3b) {
    const int N1 = NCWS;
    const int N2 = N1 + H1 * FEATP;
    const int N3 = N2 + H2 * H1;
    const int N4 = N3 + H3 * H2;
    int e = blockIdx.x * 256 + threadIdx.x;
    const float STEP = 6.28318530717958647692f / 128.0f;
    if (e < N1) {
        int j = e & 7, l = (e >> 3) & 63, ks = (e >> 9) & 3, tile = e >> 11;
        int n = tile * 16 + (l & 15);
        int k = ks * 32 + (l >> 4) * 8 + j;
        float win = 0.5f - 0.5f * cosf(STEP * (float)k);
        float v = 0.f;
        if (n < NFREQ)
            v = win * cosf(STEP * (float)((n * k) & 127)) * (1.0f / 64.0f);
        else if (n >= 80 && n < 80 + NFREQ)
            v = win * sinf(STEP * (float)(((n - 80) * k) & 127)) * (1.0f / 64.0f);
        cws[e] = f2b(v);
    } else if (e < N2) {
        int e2 = e - N1;
        int n = e2 / FEATP, k = e2 - n * FEATP;
        W1b[e2] = f2b(k < FEAT ? W1[(long)n * FEAT + k] : 0.f);
    } else if (e < N3) {
        int e2 = e - N2;
        W2b[e2] = f2b(W2[e2]);
    } else if (e < N4) {
        int e2 = e - N3;
        W3b[e2] = f2b(W3[e2]);
    }
}

// ---------------------------------------------------------------------------
// Kernel 1: STFT magnitude + sensor fusion via MFMA.
// Round-6: B-frags are coalesced 16 B/lane loads from fragment-ordered cws
// (replaces round-5's 272-B-stride gathers); softmax inlined (no wsens LDS).
// A-staging / epilogue / coalesced h0 write unchanged (verified r5).
// ---------------------------------------------------------------------------
__global__ __launch_bounds__(512, 4)
void sf_stft_fuse(const float* __restrict__ x,
                  const float* __restrict__ sw,
                  const ushort* __restrict__ cws,
                  ushort* __restrict__ h0) {
    __shared__ __align__(16) ushort xbp[NSENS * XROW];   // 36.2 KB
    __shared__ __align__(16) ushort hstage[FEATP];       // 4.4 KB

    const int b    = blockIdx.x;
    const int tid  = threadIdx.x;
    const int lane = tid & 63;
    const int wv   = tid >> 6;

    // ---- x staging: read float4 pairs, pack bf16x2, ds_write_b32
    const float4* xb4 = (const float4*)(x + (size_t)b * (LEN * NSENS));
    uint* xw = (uint*)xbp;
    for (int e = tid; e < 2048; e += 512) {
        int i = e >> 1;            // sample-pair index: l = 2i, 2i+1
        int h = e & 1;             // sensor half: s = 4h..4h+3
        float4 v0 = xb4[i * 4 + h];
        float4 v1 = xb4[i * 4 + 2 + h];
        int base = (h * 4) * (XROW / 2) + 32 + i;
        xw[base                 ] = pack2(v0.x, v1.x);
        xw[base +     (XROW / 2)] = pack2(v0.y, v1.y);
        xw[base + 2 * (XROW / 2)] = pack2(v0.z, v1.z);
        xw[base + 3 * (XROW / 2)] = pack2(v0.w, v1.w);
    }
    for (int e = tid; e < NSENS * 32; e += 512)          // left pad (64 elems)
        xw[(e >> 5) * (XROW / 2) + (e & 31)] = 0;
    for (int e = tid; e < NSENS * 76; e += 512) {        // right pad (152 elems)
        int s = e / 76;
        xw[s * (XROW / 2) + 1056 + (e - s * 76)] = 0;
    }
    if (tid < FEATP - FEAT) hstage[FEAT + tid] = 0;      // zero K-pad cols
    __syncthreads();

    // ---- MFMA phase (re/im pair-structured)
    const int col = lane & 15;
    const int q   = lane >> 4;

    // inline softmax of the 8 sensor weights; this lane needs sensors (q&1)*4..+3
    float wqa[4];
    {
        float s0 = sw[0], s1 = sw[1], s2 = sw[2], s3 = sw[3];
        float s4 = sw[4], s5 = sw[5], s6 = sw[6], s7 = sw[7];
        float mx = fmaxf(fmaxf(fmaxf(s0, s1), fmaxf(s2, s3)),
                         fmaxf(fmaxf(s4, s5), fmaxf(s6, s7)));
        float e0 = expf(s0 - mx), e1 = expf(s1 - mx), e2 = expf(s2 - mx), e3 = expf(s3 - mx);
        float e4 = expf(s4 - mx), e5 = expf(s5 - mx), e6 = expf(s6 - mx), e7 = expf(s7 - mx);
        float inv = 1.0f / (e0 + e1 + e2 + e3 + e4 + e5 + e6 + e7);
        if ((q & 1) == 0) { wqa[0] = e0 * inv; wqa[1] = e1 * inv; wqa[2] = e2 * inv; wqa[3] = e3 * inv; }
        else              { wqa[0] = e4 * inv; wqa[1] = e5 * inv; wqa[2] = e6 * inv; wqa[3] = e7 * inv; }
    }

    const ushort* abase[MT_PER_WAVE];
    #pragma unroll
    for (int mb = 0; mb < MT_PER_WAVE; ++mb) {
        int mi = wv * MT_PER_WAVE + mb;          // 0..23
        int m  = mi * 16 + col;
        int ta = m >> 3; if (ta > NFRAMES) ta = NFRAMES;   // clamp into zero pad
        int sa = m & 7;
        abase[mb] = &xbp[sa * XROW + ta * HOP + q * 8];
    }

    ushort* h0b = h0 + (size_t)b * FEATP;
    #pragma unroll 1
    for (int np = 0; np < 5; ++np) {             // re tile np, im tile np+5
        float4v accR[MT_PER_WAVE], accI[MT_PER_WAVE];
        #pragma unroll
        for (int mb = 0; mb < MT_PER_WAVE; ++mb) {
            accR[mb] = (float4v){0.f, 0.f, 0.f, 0.f};
            accI[mb] = (float4v){0.f, 0.f, 0.f, 0.f};
        }
        #pragma unroll
        for (int ks = 0; ks < 4; ++ks) {
            short8 bR = *(const short8*)&cws[(((np * 4) + ks) * 64 + lane) * 8];
            short8 bI = *(const short8*)&cws[((((np + 5) * 4) + ks) * 64 + lane) * 8];
            #pragma unroll
            for (int mb = 0; mb < MT_PER_WAVE; ++mb) {
                short8 af = *(const short8*)(abase[mb] + ks * 32);
                accR[mb] = __builtin_amdgcn_mfma_f32_16x16x32_bf16(af, bR, accR[mb], 0, 0, 0);
                accI[mb] = __builtin_amdgcn_mfma_f32_16x16x32_bf16(af, bI, accI[mb], 0, 0, 0);
            }
        }
        int f = np * 16 + col;
        #pragma unroll
        for (int mb = 0; mb < MT_PER_WAVE; ++mb) {
            float ps = 0.f;
            #pragma unroll
            for (int r = 0; r < 4; ++r) {
                float re = accR[mb][r];
                float im = accI[mb][r];
                ps += wqa[r] * sqrtf(re * re + im * im);
            }
            float tot = ps + __shfl_xor(ps, 16, 64);
            int mi = wv * MT_PER_WAVE + mb;
            int t  = mi * 2 + (q >> 1);
            if (((q & 1) == 0) && t < NFRAMES && f < NFREQ)
                hstage[f * NFRAMES + t] = f2b(tot);
        }
    }
    __syncthreads();

    // ---- coalesced h0 write (8 B/lane)
    const uint2* hsw = (const uint2*)hstage;
    uint2* ho = (uint2*)(h0b);
    for (int e = tid; e < FEATP / 4; e += 512)
        ho[e] = hsw[e];
}

// ---------------------------------------------------------------------------
// Kernel 2: single-wave bf16 MFMA NT-GEMM. One 64-thread wave per block,
// tile BMx64 (BM = MT*16), BK=64, double-buffered LDS, NO barriers — the
// only waits are vmcnt before frag reads; next-tile global_load_lds issues
// right after frag reads so the MFMA phase hides load latency.
// LDS layout: row-major 64-col rows (128 B); 16-B chunk slot s of row r
// holds k-chunk s^(r&7)  ->  b128 frag reads are conflict-free.
// M mult of BM, N mult of 64, K mult of 64.
// ---------------------------------------------------------------------------
template <int MT, int RELU>
__global__ __launch_bounds__(64)
void sf_gemm1w(const ushort* __restrict__ A, const ushort* __restrict__ W,
               const float* __restrict__ bias, ushort* __restrict__ C,
               int M, int N, int K) {
    const int BM = MT * 16;
    __shared__ __align__(16) ushort As[2][BM * 64];
    __shared__ __align__(16) ushort Bs[2][64 * 64];

    const int lane = threadIdx.x;
    const int col  = lane & 15;
    const int q    = lane >> 4;
    const int m0 = blockIdx.y * BM;
    const int n0 = blockIdx.x * 64;

    const int srow = lane >> 3;          // 0..7
    const int skch = (lane & 7) ^ srow;  // XOR-swizzled k-chunk this lane stages

    const ushort* ag = A + (size_t)(m0 + srow) * K + skch * 8;
    const ushort* wg = W + (size_t)(n0 + srow) * K + skch * 8;

    float4v acc[MT][4];
    #pragma unroll
    for (int mi = 0; mi < MT; ++mi)
        #pragma unroll
        for (int ni = 0; ni < 4; ++ni)
            acc[mi][ni] = (float4v){0.f, 0.f, 0.f, 0.f};

    // stage tile 0 into buf 0
    #pragma unroll
    for (int i = 0; i < MT * 2; ++i)
        gl_lds16(ag + (size_t)(8 * i) * K, &As[0][i * 512]);
    #pragma unroll
    for (int i = 0; i < 8; ++i)
        gl_lds16(wg + (size_t)(8 * i) * K, &Bs[0][i * 512]);

    const int nk = K >> 6;
    const int fs = col & 7;              // frag-read XOR term
    for (int kt = 0; kt < nk; ++kt) {
        const int buf = kt & 1;
        // frag reads (compiler inserts vmcnt wait for this buf's loads)
        short8 afr[2][MT], bfr[2][4];
        #pragma unroll
        for (int ks = 0; ks < 2; ++ks) {
            #pragma unroll
            for (int mi = 0; mi < MT; ++mi)
                afr[ks][mi] = *(const short8*)&As[buf][(mi * 16 + col) * 64 + (((ks * 4 + q) ^ fs) * 8)];
            #pragma unroll
            for (int ni = 0; ni < 4; ++ni)
                bfr[ks][ni] = *(const short8*)&Bs[buf][(ni * 16 + col) * 64 + (((ks * 4 + q) ^ fs) * 8)];
        }
        // prefetch next tile into the other buffer (hidden under MFMA below)
        if (kt + 1 < nk) {
            const size_t ko = (size_t)(kt + 1) * 64;
            #pragma unroll
            for (int i = 0; i < MT * 2; ++i)
                gl_lds16(ag + (size_t)(8 * i) * K + ko, &As[buf ^ 1][i * 512]);
            #pragma unroll
            for (int i = 0; i < 8; ++i)
                gl_lds16(wg + (size_t)(8 * i) * K + ko, &Bs[buf ^ 1][i * 512]);
        }
        #pragma unroll
        for (int ks = 0; ks < 2; ++ks)
            #pragma unroll
            for (int mi = 0; mi < MT; ++mi)
                #pragma unroll
                for (int ni = 0; ni < 4; ++ni)
                    acc[mi][ni] = __builtin_amdgcn_mfma_f32_16x16x32_bf16(
                        afr[ks][mi], bfr[ks][ni], acc[mi][ni], 0, 0, 0);
    }

    #pragma unroll
    for (int ni = 0; ni < 4; ++ni) {
        int n = n0 + ni * 16 + col;
        float bn = bias[n];
        #pragma unroll
        for (int mi = 0; mi < MT; ++mi) {
            int mbase = m0 + mi * 16 + q * 4;
            #pragma unroll
            for (int r = 0; r < 4; ++r) {
                float v = acc[mi][ni][r] + bn;
                if (RELU) v = fmaxf(v, 0.f);
                C[(size_t)(mbase + r) * N + n] = f2b(v);
            }
        }
    }
}

// ---------------------------------------------------------------------------
// Kernel 3: final tiny layer, fp32 out, vectorized loads.
// ---------------------------------------------------------------------------
__global__ __launch_bounds__(256)
void sf_final(const ushort* __restrict__ h3, const float* __restrict__ W4,
              const float* __restrict__ b4, float* __restrict__ out) {
    int o = blockIdx.x * 256 + threadIdx.x;
    if (o >= BATCH * NOUT) return;
    int m = o / NOUT, n = o - m * NOUT;
    const uint2*  av  = (const uint2*)(h3 + (size_t)m * H3);   // 4 bf16 per uint2
    const float4* wv4 = (const float4*)(W4 + (size_t)n * H3);
    float s = 0.f;
    #pragma unroll 8
    for (int j = 0; j < H3 / 4; ++j) {
        uint2 a = av[j];
        float4 w = wv4[j];
        s = fmaf(b2fu(a.x & 0xffffu), w.x, s);
        s = fmaf(b2fu(a.x >> 16),     w.y, s);
        s = fmaf(b2fu(a.y & 0xffffu), w.z, s);
        s = fmaf(b2fu(a.y >> 16),     w.w, s);
    }
    out[o] = s + b4[n];
}

// ---------------------------------------------------------------------------
extern "C" void kernel_launch(void* const* d_in, const int* in_sizes, int n_in,
                              void* d_out, int out_size, void* d_ws, size_t ws_size,
                              hipStream_t stream) {
    const float* x  = (const float*)d_in[0];
    const float* sw = (const float*)d_in[1];
    const float* W1 = (const float*)d_in[2];
    const float* b1 = (const float*)d_in[3];
    const float* W2 = (const float*)d_in[4];
    const float* b2 = (const float*)d_in[5];
    const float* W3 = (const float*)d_in[6];
    const float* b3 = (const float*)d_in[7];
    const float* W4 = (const float*)d_in[8];
    const float* b4 = (const float*)d_in[9];
    float* out = (float*)d_out;

    char* cur = (char*)d_ws;
    ushort* cws  = (ushort*)cur;                cur += (size_t)NCWS * 2;          // 40 KB
    ushort* h0   = (ushort*)cur;                cur += (size_t)BATCH * FEATP * 2; // 8.9 MB
    ushort* W1b  = (ushort*)cur;                cur += (size_t)H1 * FEATP * 2;    // 4.5 MB
    ushort* W2b  = (ushort*)cur;                cur += (size_t)H2 * H1 * 2;       // 1.0 MB
    ushort* W3b  = (ushort*)cur;                cur += (size_t)H3 * H2 * 2;       // 0.3 MB
    ushort* h1   = (ushort*)cur;                cur += (size_t)BATCH * H1 * 2;    // 4.2 MB
    ushort* h2   = (ushort*)cur;                cur += (size_t)BATCH * H2 * 2;    // 2.1 MB
    ushort* h3   = (ushort*)cur;                cur += (size_t)BATCH * H3 * 2;    // 1.0 MB

    const int n_prep = NCWS + H1 * FEATP + H2 * H1 + H3 * H2;
    sf_prep<<<(n_prep + 255) / 256, 256, 0, stream>>>(W1, W2, W3, cws, W1b, W2b, W3b);

    sf_stft_fuse<<<BATCH, 512, 0, stream>>>(x, sw, cws, h0);

    sf_gemm1w<4, 1><<<dim3(H1 / 64, BATCH / 64), 64, 0, stream>>>(h0, W1b, b1, h1, BATCH, H1, FEATP);
    sf_gemm1w<4, 1><<<dim3(H2 / 64, BATCH / 64), 64, 0, stream>>>(h1, W2b, b2, h2, BATCH, H2, H1);
    sf_gemm1w<2, 1><<<dim3(H3 / 64, BATCH / 32), 64, 0, stream>>>(h2, W3b, b3, h3, BATCH, H3, H2);
    sf_final<<<(BATCH * NOUT + 255) / 256, 256, 0, stream>>>(h3, W4, b4, out);
}